// Round 10
// baseline (20.572 us; speedup 1.0000x reference)
//
#include <hip/hip_runtime.h>
#include <math.h>

namespace {
constexpr int Nn = 4, Hh = 256, Ww = 256;
constexpr int HW = Hh * Ww;
constexpr int P  = Nn * HW;          // 262144 pixels
constexpr float ZFAR  = 100.0f;
constexpr float ZNEAR = 1.0f;
constexpr float INV_SIG = 1.0f / (1e-4f + 1e-8f);   // 1/(SIGMA+1e-8)
constexpr float INV_GAM = 1e4f;                     // 1/GAMMA
constexpr float EPSF    = 1e-10f;
constexpr float INV_ZR  = 1.0f / (ZFAR - ZNEAR);
}

// quad broadcast via DPP quad_perm (VALU pipe, compile-time ctrl)
#define QB_I(v, S) __builtin_amdgcn_mov_dpp((v), ((S) * 0x55), 0xf, 0xf, true)
#define QB_F(v, S) __int_as_float(QB_I(__float_as_int(v), S))

// early gather: broadcast owner's vertex ids, issue this lane's 16B chunk loads
#define LOAD_SLOT(S, QA, QB_, QC)                                              \
    {                                                                          \
        if (QB_I(fvalid, S)) {                                                 \
            const int g0 = QB_I(vx, S);                                        \
            const int g1 = QB_I(vy, S);                                        \
            const int g2 = QB_I(vz, S);                                        \
            QA = *(reinterpret_cast<const float4*>(vf + (size_t)g0 * 16) + cq); \
            QB_ = *(reinterpret_cast<const float4*>(vf + (size_t)g1 * 16) + cq); \
            QC = *(reinterpret_cast<const float4*>(vf + (size_t)g2 * 16) + cq); \
        }                                                                      \
    }

// late accumulate: broadcast owner's (now-computed) coeffs, FMA the chunks.
// coeffs are 0 when owner invalid and QA..QC are zero-init -> unguarded safe.
#define FMA_SLOT(S, QA, QB_, QC, PS)                                           \
    {                                                                          \
        const float w0 = QB_F(c0, S);                                          \
        const float w1 = QB_F(c1, S);                                          \
        const float w2 = QB_F(c2, S);                                          \
        PS.x = fmaf(w0, QA.x, fmaf(w1, QB_.x, fmaf(w2, QC.x, PS.x)));          \
        PS.y = fmaf(w0, QA.y, fmaf(w1, QB_.y, fmaf(w2, QC.y, PS.y)));          \
        PS.z = fmaf(w0, QA.z, fmaf(w1, QB_.z, fmaf(w2, QC.z, PS.z)));          \
        PS.w = fmaf(w0, QA.w, fmaf(w1, QB_.w, fmaf(w2, QC.w, PS.w)));          \
    }

// rare-path slot: load + FMA in one go (guarded on broadcast weight)
#define DO_SLOT(S, PS)                                                         \
    {                                                                          \
        const float ws = QB_F(wb2, S);                                         \
        if (ws > 0.0f) {                                                       \
            const int   g0 = QB_I(vx2, S);                                     \
            const int   g1 = QB_I(vy2, S);                                     \
            const int   g2 = QB_I(vz2, S);                                     \
            const float w0 = QB_F(e0, S);                                      \
            const float w1 = QB_F(e1, S);                                      \
            const float w2 = QB_F(e2, S);                                      \
            const float4 r0 = *(reinterpret_cast<const float4*>(vf + (size_t)g0 * 16) + cq); \
            const float4 r1 = *(reinterpret_cast<const float4*>(vf + (size_t)g1 * 16) + cq); \
            const float4 r2 = *(reinterpret_cast<const float4*>(vf + (size_t)g2 * 16) + cq); \
            PS.x = fmaf(w0, r0.x, fmaf(w1, r1.x, fmaf(w2, r2.x, PS.x)));       \
            PS.y = fmaf(w0, r0.y, fmaf(w1, r1.y, fmaf(w2, r2.y, PS.y)));       \
            PS.z = fmaf(w0, r0.z, fmaf(w1, r1.z, fmaf(w2, r2.z, PS.z)));       \
            PS.w = fmaf(w0, r0.w, fmaf(w1, r1.w, fmaf(w2, r2.w, PS.w)));       \
        }                                                                      \
    }

__global__ __launch_bounds__(256) void render_kernel(
    const float* __restrict__ vf,     // (V,16)
    const float* __restrict__ bary,   // (P,8,3)
    const float* __restrict__ dists,  // (P,8)
    const float* __restrict__ zbuf,   // (P,8)
    const int*  __restrict__ faces,   // (F,3)
    const int*  __restrict__ p2f,     // (P,8)
    float* __restrict__ out)          // (N,17,H,W)
{
    __shared__ float xp[256 * 20];    // 80B/pixel transpose scratch
    const int pp = threadIdx.x;
    const int p  = blockIdx.x * 256 + pp;
    const int cq = pp & 3;            // chunk role within quad
    const int qb = pp & ~3;           // quad base (pixel-local)

    // ---- ALL streaming loads upfront, incl. bary (coalesced, not random) ----
    const int4*   fp = reinterpret_cast<const int4*>(p2f + (size_t)p * 8);
    const float4* zp = reinterpret_cast<const float4*>(zbuf + (size_t)p * 8);
    const float4* dp = reinterpret_cast<const float4*>(dists + (size_t)p * 8);
    const float4* bp = reinterpret_cast<const float4*>(bary + (size_t)p * 24);
    int4   fA = fp[0], fB = fp[1];
    float4 zA = zp[0], zB = zp[1];
    float4 dA = dp[0], dB = dp[1];
    float4 bv0 = bp[0], bv1 = bp[1], bv2 = bp[2];
    float4 bv3 = bp[3], bv4 = bp[4], bv5 = bp[5];

    int fk[8] = {fA.x, fA.y, fA.z, fA.w, fB.x, fB.y, fB.z, fB.w};
    float zraw[8] = {zA.x, zA.y, zA.z, zA.w, zB.x, zB.y, zB.z, zB.w};

    // ---- z_inv, zmax, argmax-by-z (softmax-free survivor selection) ----
    float zi[8];
    float zmax = EPSF, zbest = 0.0f;
    int ksel = -1, fsel = 0;
#pragma unroll
    for (int k = 0; k < 8; ++k) {
        const bool valid = fk[k] >= 0;
        float zv = valid ? (ZFAR - zraw[k]) * INV_ZR : 0.0f;
        zi[k] = zv;
        zmax = fmaxf(zmax, zv);
        const bool better = valid && (zv > zbest);
        zbest = better ? zv : zbest;
        ksel  = better ? k : ksel;
        fsel  = better ? fk[k] : fsel;
    }
    const int fvalid = (ksel >= 0) ? 1 : 0;

    // ---- extract selected bary from registers (static chain; bc dies here) ----
    float b0, b1, b2;
    {
        const float bc[24] = {bv0.x, bv0.y, bv0.z, bv0.w,
                              bv1.x, bv1.y, bv1.z, bv1.w,
                              bv2.x, bv2.y, bv2.z, bv2.w,
                              bv3.x, bv3.y, bv3.z, bv3.w,
                              bv4.x, bv4.y, bv4.z, bv4.w,
                              bv5.x, bv5.y, bv5.z, bv5.w};
        float t0 = 0.0f, t1 = 0.0f, t2 = 0.0f;
#pragma unroll
        for (int k = 0; k < 8; ++k) {
            t0 = (k == ksel) ? bc[k * 3 + 0] : t0;
            t1 = (k == ksel) ? bc[k * 3 + 1] : t1;
            t2 = (k == ksel) ? bc[k * 3 + 2] : t2;
        }
        b0 = t0; b1 = t1; b2 = t2;
    }

    // ---- owner issues faces load for the selected slot ----
    int vx = 0, vy = 0, vz = 0;
    if (fvalid) {
        const int4 vidx = *reinterpret_cast<const int4*>(faces + (size_t)fsel * 3);
        vx = vidx.x; vy = vidx.y; vz = vidx.z;
    }

    // ---- staggered early vf loads: slots 0-1 before softmax (hidden) ----
    const float4 z4 = make_float4(0.f, 0.f, 0.f, 0.f);
    float4 q0a = z4, q0b = z4, q0c = z4;
    float4 q1a = z4, q1b = z4, q1c = z4;
    LOAD_SLOT(0, q0a, q0b, q0c)
    LOAD_SLOT(1, q1a, q1b, q1c)

    // ---- softmax (overlaps slot 0-1 gather latency) ----
    float dk[8] = {dA.x, dA.y, dA.z, dA.w, dB.x, dB.y, dB.z, dB.w};
    const float delta = fmaxf(__expf((EPSF - zmax) * INV_GAM), EPSF);
    float denom = delta;
    float keep  = 1.0f;
    float wv[8];
#pragma unroll
    for (int k = 0; k < 8; ++k) {
        const bool valid = fk[k] >= 0;
        float pr = valid ? 1.0f / (1.0f + __expf(dk[k] * INV_SIG)) : 0.0f;
        keep *= (1.0f - pr);
        float w = pr * __expf((zi[k] - zmax) * INV_GAM);
        wv[k] = w;
        denom += w;
    }

    // wb = wv[ksel] via static cndmask chain
    float wb = 0.0f;
#pragma unroll
    for (int k = 0; k < 8; ++k) wb = (k == ksel) ? wv[k] : wb;
    const float c0 = wb * b0, c1 = wb * b1, c2 = wb * b2;

    // ---- interleaved FMA / LOAD: retire slot regs before loading next ----
    float4 ps0 = z4, ps1 = z4, ps2 = z4, ps3 = z4;
    FMA_SLOT(0, q0a, q0b, q0c, ps0)
    float4 q2a = z4, q2b = z4, q2c = z4;
    LOAD_SLOT(2, q2a, q2b, q2c)
    FMA_SLOT(1, q1a, q1b, q1c, ps1)
    float4 q3a = z4, q3b = z4, q3c = z4;
    LOAD_SLOT(3, q3a, q3b, q3c)
    FMA_SLOT(2, q2a, q2b, q2c, ps2)
    FMA_SLOT(3, q3a, q3b, q3c, ps3)

    // ---- rare path: remaining w>0 slots (near-ties only; lazy bary ok) ----
#pragma unroll
    for (int k = 0; k < 8; ++k) wv[k] = (k == ksel) ? 0.0f : wv[k];
    bool more = false;
#pragma unroll
    for (int k = 0; k < 8; ++k) more = more || (wv[k] > 0.0f);

    if (__any(more)) {
        while (true) {
            float wb2 = 0.0f;
            int fsel2 = 0, ksel2 = -1;
#pragma unroll
            for (int k = 0; k < 8; ++k) {
                const bool better = wv[k] > wb2;
                wb2   = better ? wv[k] : wb2;
                fsel2 = better ? fk[k] : fsel2;
                ksel2 = better ? k : ksel2;
            }
            if (!__any(wb2 > 0.0f)) break;

            int vx2 = 0, vy2 = 0, vz2 = 0;
            float e0 = 0.0f, e1 = 0.0f, e2 = 0.0f;
            if (wb2 > 0.0f) {
                const int4 vidx = *reinterpret_cast<const int4*>(faces + (size_t)fsel2 * 3);
                const float4 bq = *reinterpret_cast<const float4*>(
                    bary + (size_t)p * 24 + ksel2 * 3);
                vx2 = vidx.x; vy2 = vidx.y; vz2 = vidx.z;
                e0 = wb2 * bq.x; e1 = wb2 * bq.y; e2 = wb2 * bq.z;
            }
            DO_SLOT(0, ps0)
            DO_SLOT(1, ps1)
            DO_SLOT(2, ps2)
            DO_SLOT(3, ps3)
#pragma unroll
            for (int k = 0; k < 8; ++k)
                wv[k] = (k == ksel2) ? 0.0f : wv[k];
        }
    }

    // ---- 4x4 quad transpose via LDS: distributed chunks -> per-pixel ----
    *reinterpret_cast<float4*>(&xp[(qb + 0) * 20 + cq * 4]) = ps0;
    *reinterpret_cast<float4*>(&xp[(qb + 1) * 20 + cq * 4]) = ps1;
    *reinterpret_cast<float4*>(&xp[(qb + 2) * 20 + cq * 4]) = ps2;
    *reinterpret_cast<float4*>(&xp[(qb + 3) * 20 + cq * 4]) = ps3;
    __syncthreads();
    const float4 a0 = *reinterpret_cast<const float4*>(&xp[pp * 20 + 0]);
    const float4 a1 = *reinterpret_cast<const float4*>(&xp[pp * 20 + 4]);
    const float4 a2 = *reinterpret_cast<const float4*>(&xp[pp * 20 + 8]);
    const float4 a3 = *reinterpret_cast<const float4*>(&xp[pp * 20 + 12]);

    // ---- epilogue: divide by denom, store channel-major ----
    const float invden = 1.0f / denom;
    const int n  = p >> 16;           // p / HW (HW = 65536)
    const int hw = p & (HW - 1);
    float* o = out + (size_t)n * 17 * HW + hw;
    o[(size_t)0  * HW] = a0.x * invden;
    o[(size_t)1  * HW] = a0.y * invden;
    o[(size_t)2  * HW] = a0.z * invden;
    o[(size_t)3  * HW] = a0.w * invden;
    o[(size_t)4  * HW] = a1.x * invden;
    o[(size_t)5  * HW] = a1.y * invden;
    o[(size_t)6  * HW] = a1.z * invden;
    o[(size_t)7  * HW] = a1.w * invden;
    o[(size_t)8  * HW] = a2.x * invden;
    o[(size_t)9  * HW] = a2.y * invden;
    o[(size_t)10 * HW] = a2.z * invden;
    o[(size_t)11 * HW] = a2.w * invden;
    o[(size_t)12 * HW] = a3.x * invden;
    o[(size_t)13 * HW] = a3.y * invden;
    o[(size_t)14 * HW] = a3.z * invden;
    o[(size_t)15 * HW] = a3.w * invden;
    o[(size_t)16 * HW] = 1.0f - keep;   // alpha
}

extern "C" void kernel_launch(void* const* d_in, const int* in_sizes, int n_in,
                              void* d_out, int out_size, void* d_ws, size_t ws_size,
                              hipStream_t stream) {
    const float* vf    = (const float*)d_in[0];
    const float* bary  = (const float*)d_in[1];
    const float* dists = (const float*)d_in[2];
    const float* zbuf  = (const float*)d_in[3];
    const int*   faces = (const int*)d_in[4];
    const int*   p2f   = (const int*)d_in[5];
    float* out = (float*)d_out;

    render_kernel<<<dim3(P / 256), dim3(256), 0, stream>>>(
        vf, bary, dists, zbuf, faces, p2f, out);
}

// Round 11
// 20.330 us; speedup vs baseline: 1.0119x; 1.0119x over previous
//
#include <hip/hip_runtime.h>
#include <math.h>

namespace {
constexpr int Nn = 4, Hh = 256, Ww = 256;
constexpr int HW = Hh * Ww;
constexpr int P  = Nn * HW;          // 262144 pixels
constexpr float ZFAR  = 100.0f;
constexpr float ZNEAR = 1.0f;
constexpr float INV_SIG = 1.0f / (1e-4f + 1e-8f);   // 1/(SIGMA+1e-8)
constexpr float INV_GAM = 1e4f;                     // 1/GAMMA
constexpr float EPSF    = 1e-10f;
constexpr float INV_ZR  = 1.0f / (ZFAR - ZNEAR);
// w2 > 0 requires exp((z2-z1)*1e4) above denormal floor: z1-z2 <= ~0.0104
constexpr float ZTIE    = 0.0104f;
}

// quad broadcast via DPP quad_perm (VALU pipe, compile-time ctrl)
#define QB_I(v, S) __builtin_amdgcn_mov_dpp((v), ((S) * 0x55), 0xf, 0xf, true)
#define QB_F(v, S) __int_as_float(QB_I(__float_as_int(v), S))

// early gather: broadcast owner's vertex ids, issue this lane's 16B chunk loads
#define LOAD_SLOT(S, QA, QB_, QC)                                              \
    {                                                                          \
        if (QB_I(fvalid, S)) {                                                 \
            const int g0 = QB_I(vx, S);                                        \
            const int g1 = QB_I(vy, S);                                        \
            const int g2 = QB_I(vz, S);                                        \
            QA = *(reinterpret_cast<const float4*>(vf + (size_t)g0 * 16) + cq); \
            QB_ = *(reinterpret_cast<const float4*>(vf + (size_t)g1 * 16) + cq); \
            QC = *(reinterpret_cast<const float4*>(vf + (size_t)g2 * 16) + cq); \
        }                                                                      \
    }

// late accumulate: broadcast owner's coeffs, FMA the prefetched chunks.
// coeffs are 0 when owner invalid and QA..QC are zero-init -> unguarded safe.
#define FMA_SLOT(S, QA, QB_, QC, PS)                                           \
    {                                                                          \
        const float w0 = QB_F(c0, S);                                          \
        const float w1 = QB_F(c1, S);                                          \
        const float w2_ = QB_F(c2, S);                                         \
        PS.x = fmaf(w0, QA.x, fmaf(w1, QB_.x, fmaf(w2_, QC.x, PS.x)));         \
        PS.y = fmaf(w0, QA.y, fmaf(w1, QB_.y, fmaf(w2_, QC.y, PS.y)));         \
        PS.z = fmaf(w0, QA.z, fmaf(w1, QB_.z, fmaf(w2_, QC.z, PS.z)));         \
        PS.w = fmaf(w0, QA.w, fmaf(w1, QB_.w, fmaf(w2_, QC.w, PS.w)));         \
    }

// generic load+FMA slot, guarded on broadcast weight (names parameterized)
#define DO_SLOT_G(S, WSRC, VX, VY, VZ, E0, E1, E2, PS)                         \
    {                                                                          \
        const float ws = QB_F(WSRC, S);                                        \
        if (ws > 0.0f) {                                                       \
            const int   g0 = QB_I(VX, S);                                      \
            const int   g1 = QB_I(VY, S);                                      \
            const int   g2 = QB_I(VZ, S);                                      \
            const float w0 = QB_F(E0, S);                                      \
            const float w1 = QB_F(E1, S);                                      \
            const float w2_ = QB_F(E2, S);                                     \
            const float4 r0 = *(reinterpret_cast<const float4*>(vf + (size_t)g0 * 16) + cq); \
            const float4 r1 = *(reinterpret_cast<const float4*>(vf + (size_t)g1 * 16) + cq); \
            const float4 r2 = *(reinterpret_cast<const float4*>(vf + (size_t)g2 * 16) + cq); \
            PS.x = fmaf(w0, r0.x, fmaf(w1, r1.x, fmaf(w2_, r2.x, PS.x)));      \
            PS.y = fmaf(w0, r0.y, fmaf(w1, r1.y, fmaf(w2_, r2.y, PS.y)));      \
            PS.z = fmaf(w0, r0.z, fmaf(w1, r1.z, fmaf(w2_, r2.z, PS.z)));      \
            PS.w = fmaf(w0, r0.w, fmaf(w1, r1.w, fmaf(w2_, r2.w, PS.w)));      \
        }                                                                      \
    }

__global__ __launch_bounds__(256, 4) void render_kernel(
    const float* __restrict__ vf,     // (V,16)
    const float* __restrict__ bary,   // (P,8,3)
    const float* __restrict__ dists,  // (P,8)
    const float* __restrict__ zbuf,   // (P,8)
    const int*  __restrict__ faces,   // (F,3)
    const int*  __restrict__ p2f,     // (P,8)
    float* __restrict__ out)          // (N,17,H,W)
{
    __shared__ float xp[256 * 20];    // transpose scratch; intra-wave use only
    const int pp = threadIdx.x;
    const int p  = blockIdx.x * 256 + pp;
    const int cq = pp & 3;            // chunk role within quad
    const int qb = pp & ~3;           // quad base (pixel-local)

    // ---- streaming loads (lazy bary: only selected slots are read) ----
    const int4*   fp = reinterpret_cast<const int4*>(p2f + (size_t)p * 8);
    const float4* zp = reinterpret_cast<const float4*>(zbuf + (size_t)p * 8);
    const float4* dp = reinterpret_cast<const float4*>(dists + (size_t)p * 8);
    int4   fA = fp[0], fB = fp[1];
    float4 zA = zp[0], zB = zp[1];
    float4 dA = dp[0], dB = dp[1];

    int fk[8] = {fA.x, fA.y, fA.z, fA.w, fB.x, fB.y, fB.z, fB.w};
    float zraw[8] = {zA.x, zA.y, zA.z, zA.w, zB.x, zB.y, zB.z, zB.w};

    // ---- z pass: z_inv + TOP-2 selection by z (valid-only, static chains) ----
    float zi[8];
    float z1v = -1.0f, z2v = -1.0f;
    int k1 = -1, k2 = -1, f1 = 0, f2 = 0;
#pragma unroll
    for (int k = 0; k < 8; ++k) {
        const bool valid = fk[k] >= 0;
        float zv = valid ? (ZFAR - zraw[k]) * INV_ZR : 0.0f;
        zi[k] = zv;
        const float zvm = valid ? zv : -1.0f;
        const bool bet1 = zvm > z1v;
        const bool bet2 = zvm > z2v;
        const float nz2 = bet1 ? z1v : (bet2 ? zvm : z2v);
        const int   nk2 = bet1 ? k1  : (bet2 ? k   : k2);
        const int   nf2 = bet1 ? f1  : (bet2 ? fk[k] : f2);
        z1v = bet1 ? zvm   : z1v;
        k1  = bet1 ? k     : k1;
        f1  = bet1 ? fk[k] : f1;
        z2v = nz2; k2 = nk2; f2 = nf2;
    }
    const float zmax = fmaxf(z1v, EPSF);
    const int fvalid = (k1 >= 0) ? 1 : 0;

    // ---- owner issues faces + bary for BEST immediately ----
    int vx = 0, vy = 0, vz = 0;
    float b0 = 0.0f, b1 = 0.0f, b2 = 0.0f;
    if (fvalid) {
        const int4 vidx = *reinterpret_cast<const int4*>(faces + (size_t)f1 * 3);
        const float4 bq = *reinterpret_cast<const float4*>(bary + (size_t)p * 24 + k1 * 3);
        vx = vidx.x; vy = vidx.y; vz = vidx.z;
        b0 = bq.x; b1 = bq.y; b2 = bq.z;
    }

    // ---- pre-test 2nd survivor (underflow window) + issue its loads early ----
    const bool pt2 = (k2 >= 0) && (z2v >= z1v - ZTIE);
    int vx2 = 0, vy2 = 0, vz2 = 0;
    float s0 = 0.0f, s1 = 0.0f, s2 = 0.0f;
    if (pt2) {
        const int4 vidx = *reinterpret_cast<const int4*>(faces + (size_t)f2 * 3);
        const float4 bq = *reinterpret_cast<const float4*>(bary + (size_t)p * 24 + k2 * 3);
        vx2 = vidx.x; vy2 = vidx.y; vz2 = vidx.z;
        s0 = bq.x; s1 = bq.y; s2 = bq.z;
    }

    // ---- staggered early vf loads: slots 0-1 before softmax (hidden) ----
    const float4 z4 = make_float4(0.f, 0.f, 0.f, 0.f);
    float4 q0a = z4, q0b = z4, q0c = z4;
    float4 q1a = z4, q1b = z4, q1c = z4;
    LOAD_SLOT(0, q0a, q0b, q0c)
    LOAD_SLOT(1, q1a, q1b, q1c)

    // ---- softmax (overlaps gather latency) ----
    float dk[8] = {dA.x, dA.y, dA.z, dA.w, dB.x, dB.y, dB.z, dB.w};
    const float delta = fmaxf(__expf((EPSF - zmax) * INV_GAM), EPSF);
    float denom = delta;
    float keep  = 1.0f;
    float wv[8];
#pragma unroll
    for (int k = 0; k < 8; ++k) {
        const bool valid = fk[k] >= 0;
        float pr = valid ? 1.0f / (1.0f + __expf(dk[k] * INV_SIG)) : 0.0f;
        keep *= (1.0f - pr);
        float w = pr * __expf((zi[k] - zmax) * INV_GAM);
        wv[k] = w;
        denom += w;
    }

    // ---- weights for best & 2nd via static chains ----
    float wb = 0.0f, w2 = 0.0f;
#pragma unroll
    for (int k = 0; k < 8; ++k) {
        wb = (k == k1) ? wv[k] : wb;
        w2 = (k == k2) ? wv[k] : w2;
    }
    const float c0 = wb * b0, c1 = wb * b1, c2 = wb * b2;
    const float e0 = w2 * s0, e1 = w2 * s1, e2 = w2 * s2;

    // ---- best: interleaved FMA / LOAD ----
    float4 ps0 = z4, ps1 = z4, ps2 = z4, ps3 = z4;
    FMA_SLOT(0, q0a, q0b, q0c, ps0)
    float4 q2a = z4, q2b = z4, q2c = z4;
    LOAD_SLOT(2, q2a, q2b, q2c)
    FMA_SLOT(1, q1a, q1b, q1c, ps1)
    float4 q3a = z4, q3b = z4, q3c = z4;
    LOAD_SLOT(3, q3a, q3b, q3c)
    FMA_SLOT(2, q2a, q2b, q2c, ps2)
    FMA_SLOT(3, q3a, q3b, q3c, ps3)

    // ---- 2nd survivor: load+FMA, per-slot guarded (~6% of quads active) ----
    DO_SLOT_G(0, w2, vx2, vy2, vz2, e0, e1, e2, ps0)
    DO_SLOT_G(1, w2, vx2, vy2, vz2, e0, e1, e2, ps1)
    DO_SLOT_G(2, w2, vx2, vy2, vz2, e0, e1, e2, ps2)
    DO_SLOT_G(3, w2, vx2, vy2, vz2, e0, e1, e2, ps3)

    // ---- residual (>=3 survivors): ultra-rare, wave-gated general loop ----
#pragma unroll
    for (int k = 0; k < 8; ++k)
        wv[k] = (k == k1 || k == k2) ? 0.0f : wv[k];
    bool more = false;
#pragma unroll
    for (int k = 0; k < 8; ++k) more = more || (wv[k] > 0.0f);

    if (__any(more)) {
        while (true) {
            float wbr = 0.0f;
            int fselr = 0, kselr = -1;
#pragma unroll
            for (int k = 0; k < 8; ++k) {
                const bool better = wv[k] > wbr;
                wbr   = better ? wv[k] : wbr;
                fselr = better ? fk[k] : fselr;
                kselr = better ? k : kselr;
            }
            if (!__any(wbr > 0.0f)) break;

            int vxr = 0, vyr = 0, vzr = 0;
            float r0 = 0.0f, r1 = 0.0f, r2 = 0.0f;
            if (wbr > 0.0f) {
                const int4 vidx = *reinterpret_cast<const int4*>(faces + (size_t)fselr * 3);
                const float4 bq = *reinterpret_cast<const float4*>(
                    bary + (size_t)p * 24 + kselr * 3);
                vxr = vidx.x; vyr = vidx.y; vzr = vidx.z;
                r0 = wbr * bq.x; r1 = wbr * bq.y; r2 = wbr * bq.z;
            }
            DO_SLOT_G(0, wbr, vxr, vyr, vzr, r0, r1, r2, ps0)
            DO_SLOT_G(1, wbr, vxr, vyr, vzr, r0, r1, r2, ps1)
            DO_SLOT_G(2, wbr, vxr, vyr, vzr, r0, r1, r2, ps2)
            DO_SLOT_G(3, wbr, vxr, vyr, vzr, r0, r1, r2, ps3)
#pragma unroll
            for (int k = 0; k < 8; ++k)
                wv[k] = (k == kselr) ? 0.0f : wv[k];
        }
    }

    // ---- 4x4 quad transpose via LDS: INTRA-WAVE, so NO barrier needed ----
    *reinterpret_cast<float4*>(&xp[(qb + 0) * 20 + cq * 4]) = ps0;
    *reinterpret_cast<float4*>(&xp[(qb + 1) * 20 + cq * 4]) = ps1;
    *reinterpret_cast<float4*>(&xp[(qb + 2) * 20 + cq * 4]) = ps2;
    *reinterpret_cast<float4*>(&xp[(qb + 3) * 20 + cq * 4]) = ps3;
    // compiler inserts lgkmcnt wait; quad lanes are in the same wave (lockstep)
    const float4 a0 = *reinterpret_cast<const float4*>(&xp[pp * 20 + 0]);
    const float4 a1 = *reinterpret_cast<const float4*>(&xp[pp * 20 + 4]);
    const float4 a2 = *reinterpret_cast<const float4*>(&xp[pp * 20 + 8]);
    const float4 a3 = *reinterpret_cast<const float4*>(&xp[pp * 20 + 12]);

    // ---- epilogue: divide by denom, store channel-major ----
    const float invden = 1.0f / denom;
    const int n  = p >> 16;           // p / HW (HW = 65536)
    const int hw = p & (HW - 1);
    float* o = out + (size_t)n * 17 * HW + hw;
    o[(size_t)0  * HW] = a0.x * invden;
    o[(size_t)1  * HW] = a0.y * invden;
    o[(size_t)2  * HW] = a0.z * invden;
    o[(size_t)3  * HW] = a0.w * invden;
    o[(size_t)4  * HW] = a1.x * invden;
    o[(size_t)5  * HW] = a1.y * invden;
    o[(size_t)6  * HW] = a1.z * invden;
    o[(size_t)7  * HW] = a1.w * invden;
    o[(size_t)8  * HW] = a2.x * invden;
    o[(size_t)9  * HW] = a2.y * invden;
    o[(size_t)10 * HW] = a2.z * invden;
    o[(size_t)11 * HW] = a2.w * invden;
    o[(size_t)12 * HW] = a3.x * invden;
    o[(size_t)13 * HW] = a3.y * invden;
    o[(size_t)14 * HW] = a3.z * invden;
    o[(size_t)15 * HW] = a3.w * invden;
    o[(size_t)16 * HW] = 1.0f - keep;   // alpha
}

extern "C" void kernel_launch(void* const* d_in, const int* in_sizes, int n_in,
                              void* d_out, int out_size, void* d_ws, size_t ws_size,
                              hipStream_t stream) {
    const float* vf    = (const float*)d_in[0];
    const float* bary  = (const float*)d_in[1];
    const float* dists = (const float*)d_in[2];
    const float* zbuf  = (const float*)d_in[3];
    const int*   faces = (const int*)d_in[4];
    const int*   p2f   = (const int*)d_in[5];
    float* out = (float*)d_out;

    render_kernel<<<dim3(P / 256), dim3(256), 0, stream>>>(
        vf, bary, dists, zbuf, faces, p2f, out);
}